// Round 3
// baseline (1630.698 us; speedup 1.0000x reference)
//
#include <hip/hip_runtime.h>
#include <hip/hip_bf16.h>
#include <cstdint>
#include <cstddef>

#define DEVINL __device__ __forceinline__

typedef _Float16 f16x8 __attribute__((ext_vector_type(8)));
typedef _Float16 f16x2 __attribute__((ext_vector_type(2)));
typedef float    f32x4 __attribute__((ext_vector_type(4)));

// B=4, T=256, U=64, E=H=J=512, O=1024, gate rows 2048

DEVINL float fsigm(float x) {
    float e = __expf(-x);
    return __builtin_amdgcn_rcpf(1.f + e);
}
DEVINL float ftanh(float x) {
    float e = __expf(2.f * x);
    return 1.f - 2.f * __builtin_amdgcn_rcpf(e + 1.f);
}

DEVINL float dot8(f16x8 w, f16x8 x, float acc) {
    f16x2 w0{w[0], w[1]}, w1{w[2], w[3]}, w2{w[4], w[5]}, w3{w[6], w[7]};
    f16x2 x0{x[0], x[1]}, x1{x[2], x[3]}, x2{x[4], x[5]}, x3{x[6], x[7]};
    acc = __builtin_amdgcn_fdot2(w0, x0, acc, false);
    acc = __builtin_amdgcn_fdot2(w1, x1, acc, false);
    acc = __builtin_amdgcn_fdot2(w2, x2, acc, false);
    acc = __builtin_amdgcn_fdot2(w3, x3, acc, false);
    return acc;
}

// 16B from LLC via two 8B relaxed agent atomic loads (device-coherent path)
DEVINL f16x8 ld_h16(const _Float16* base) {
    const uint64_t* q = (const uint64_t*)base;
    uint64_t lo = __hip_atomic_load(q,     __ATOMIC_RELAXED, __HIP_MEMORY_SCOPE_AGENT);
    uint64_t hi = __hip_atomic_load(q + 1, __ATOMIC_RELAXED, __HIP_MEMORY_SCOPE_AGENT);
    union { uint64_t u[2]; f16x8 v; } u;
    u.u[0] = lo; u.u[1] = hi;
    return u.v;
}

// ---------------------------------------------------------------------------
// prep: cast LSTM weights + W_out to f16
// dst layout (elements): [Wih0 1M | Whh0 1M | Wih1 1M | Whh1 1M | Wout 0.5M]
// ---------------------------------------------------------------------------
__global__ void k_prep_f16(const float* __restrict__ wih0, const float* __restrict__ whh0,
                           const float* __restrict__ wih1, const float* __restrict__ whh1,
                           const float* __restrict__ wout, _Float16* __restrict__ dst, int total) {
    int stride = gridDim.x * blockDim.x;
    for (int i = blockIdx.x * blockDim.x + threadIdx.x; i < total; i += stride) {
        const float* src; int off;
        if      (i < (1 << 20)) { src = wih0; off = i; }
        else if (i < (2 << 20)) { src = whh0; off = i - (1 << 20); }
        else if (i < (3 << 20)) { src = wih1; off = i - (2 << 20); }
        else if (i < (4 << 20)) { src = whh1; off = i - (3 << 20); }
        else                    { src = wout; off = i - (4 << 20); }
        dst[i] = (_Float16)src[off];
    }
}

// ---------------------------------------------------------------------------
// embedding gather (f16 output): Ebuf[(u*4+b)*512 + e] = embed[ys_in[b][u]][e]
// ---------------------------------------------------------------------------
__global__ void k_embed(const float* __restrict__ embed, const int* __restrict__ ys,
                        _Float16* __restrict__ Ebuf) {
    int bu = blockIdx.x;           // 0..255
    int b = bu >> 6, u = bu & 63;
    int tok = (u == 0) ? 0 : ys[b * 63 + (u - 1)];
    const float* src = embed + (size_t)tok * 512;
    _Float16* dst = Ebuf + ((size_t)(u * 4 + b)) * 512;
    int t2 = threadIdx.x * 2;
    float2 v = *(const float2*)(src + t2);
    dst[t2]     = (_Float16)v.x;
    dst[t2 + 1] = (_Float16)v.y;
}

// ---------------------------------------------------------------------------
// persistent 2-layer LSTM. 64 blocks x 256 threads.
// blocks 0..31: layer0, 32..63: layer1 (lagging one round).
// Block owns 16 hidden units -> 64 gate rows x 4 batches.
//
// v4: poll-phase cost is the bottleneck (v1=1 phase 11.2us/rnd,
// v3=3 phases 16.6us/rnd => ~3-5us/phase). So:
//  * hot-spin polls (no s_sleep - wakeup quantum suspected >> 64cy)
//  * L1: ONE combined 64-lane poll (L0 flags >= s AND peers >= s)
//  * no LDS xh staging: each thread loads its own k-slices of x/h
//    directly into registers (8B relaxed agent atomics / cached Ebuf)
//  * L0 computes ih dots (static Ebuf) before its poll; free-runs via
//    history-indexed H0h
// ---------------------------------------------------------------------------
__global__ void __launch_bounds__(256, 1) k_lstm(
        const _Float16* __restrict__ WF,
        const float* __restrict__ bih0, const float* __restrict__ bhh0,
        const float* __restrict__ bih1, const float* __restrict__ bhh1,
        const _Float16* __restrict__ Ebuf,
        _Float16* __restrict__ H0h, _Float16* __restrict__ H1h,
        float* __restrict__ H1, int* __restrict__ flags) {
    const int blk   = blockIdx.x;
    const int layer = blk >> 5;
    const int ublk  = blk & 31;
    const int unit0 = ublk * 16;
    const int tid   = threadIdx.x;
    const int rg    = tid >> 5;          // 0..7 : row group (8 rows)
    const int kp    = tid & 31;          // 0..31: k phase

    // cell owned after reduce-scatter
    const int rb_own   = rg * 8 + (kp >> 2);                 // 0..63
    const int b_own    = kp & 3;
    const int grow_own = ((rb_own >> 4) << 9) + unit0 + (rb_own & 15);

    const _Float16* WihL = WF + (size_t)(layer ? (2u << 20) : 0u);
    const _Float16* WhhL = WF + (size_t)(layer ? (3u << 20) : (1u << 20));

    // ---- persistent weights in VGPRs ----
    f16x8 wA[8][2];   // Wih rows
    f16x8 wB[8][2];   // Whh rows
    #pragma unroll
    for (int r = 0; r < 8; ++r) {
        int rb = rg * 8 + r;
        int grow = ((rb >> 4) << 9) + unit0 + (rb & 15);
        const _Float16* irow = WihL + (size_t)grow * 512;
        const _Float16* hrow = WhhL + (size_t)grow * 512;
        wA[r][0] = *(const f16x8*)(irow + kp * 8);
        wA[r][1] = *(const f16x8*)(irow + 256 + kp * 8);
        wB[r][0] = *(const f16x8*)(hrow + kp * 8);
        wB[r][1] = *(const f16x8*)(hrow + 256 + kp * 8);
    }
    const float* biL = layer ? bih1 : bih0;
    const float* bhL = layer ? bhh1 : bhh0;
    const float bsum = biL[grow_own] + bhL[grow_own];

    __shared__ float g_lds[64 * 4];      // gates [rb][b]

    float c_reg = 0.f;
    const int c0 = kp * 8;               // f16 elem offset, chunk 0
    const int c1 = 256 + kp * 8;         // f16 elem offset, chunk 1
    const int s_lo = layer ? 1 : 0;
    const int s_hi = layer ? 64 : 63;

    for (int s = s_lo; s <= s_hi; ++s) {
        const int st = s - s_lo;         // L0: st=s ; L1: st=s-1

        float p[8][4];
        #pragma unroll
        for (int r = 0; r < 8; ++r)
            #pragma unroll
            for (int b = 0; b < 4; ++b) p[r][b] = 0.f;

        if (!layer) {
            // ---- x slices from Ebuf (cached) + ih dots BEFORE the wait ----
            #pragma unroll
            for (int b = 0; b < 4; ++b) {
                const _Float16* er = Ebuf + ((size_t)(st * 4 + b)) * 512;
                f16x8 x0 = *(const f16x8*)(er + c0);
                f16x8 x1 = *(const f16x8*)(er + c1);
                #pragma unroll
                for (int r = 0; r < 8; ++r) {
                    p[r][b] = dot8(wA[r][0], x0, p[r][b]);
                    p[r][b] = dot8(wA[r][1], x1, p[r][b]);
                }
            }
            if (s > 0) {
                // ---- hot-spin: own group >= s ----
                if (tid < 32) {
                    for (;;) {
                        int f = __hip_atomic_load(flags + tid * 16, __ATOMIC_RELAXED,
                                                  __HIP_MEMORY_SCOPE_AGENT);
                        if (__ballot(f < s) == 0ull) break;
                    }
                }
                __syncthreads();
                // ---- h slices direct from LLC + hh dots ----
                f16x8 hv[4][2];
                #pragma unroll
                for (int b = 0; b < 4; ++b) {
                    const _Float16* hr = H0h + ((size_t)((st - 1) * 4 + b)) * 512;
                    hv[b][0] = ld_h16(hr + c0);
                    hv[b][1] = ld_h16(hr + c1);
                }
                #pragma unroll
                for (int b = 0; b < 4; ++b)
                    #pragma unroll
                    for (int r = 0; r < 8; ++r) {
                        p[r][b] = dot8(wB[r][0], hv[b][0], p[r][b]);
                        p[r][b] = dot8(wB[r][1], hv[b][1], p[r][b]);
                    }
            }
        } else {
            // ---- ONE combined poll: L0 blocks >= s AND own peers >= s ----
            if (tid < 64) {
                const int thr = (tid < 32) ? s : ((s > 1) ? s : 0);
                const int* fp = flags + tid * 16;
                for (;;) {
                    int f = __hip_atomic_load(fp, __ATOMIC_RELAXED,
                                              __HIP_MEMORY_SCOPE_AGENT);
                    if (__ballot(f < thr) == 0ull) break;
                }
            }
            __syncthreads();
            // ---- all loads issued together: x = h0[st], h = h1[st-1] ----
            f16x8 xv[4][2], hv[4][2];
            #pragma unroll
            for (int b = 0; b < 4; ++b) {
                const _Float16* xr = H0h + ((size_t)(st * 4 + b)) * 512;
                xv[b][0] = ld_h16(xr + c0);
                xv[b][1] = ld_h16(xr + c1);
            }
            if (st > 0) {
                #pragma unroll
                for (int b = 0; b < 4; ++b) {
                    const _Float16* hr = H1h + ((size_t)((st - 1) * 4 + b)) * 512;
                    hv[b][0] = ld_h16(hr + c0);
                    hv[b][1] = ld_h16(hr + c1);
                }
            }
            #pragma unroll
            for (int b = 0; b < 4; ++b)
                #pragma unroll
                for (int r = 0; r < 8; ++r) {
                    p[r][b] = dot8(wA[r][0], xv[b][0], p[r][b]);
                    p[r][b] = dot8(wA[r][1], xv[b][1], p[r][b]);
                }
            if (st > 0) {
                #pragma unroll
                for (int b = 0; b < 4; ++b)
                    #pragma unroll
                    for (int r = 0; r < 8; ++r) {
                        p[r][b] = dot8(wB[r][0], hv[b][0], p[r][b]);
                        p[r][b] = dot8(wB[r][1], hv[b][1], p[r][b]);
                    }
            }
        }

        // ---- butterfly reduce-scatter over 32 kp lanes: lane kp owns t=kp ----
        float a[32];
        #pragma unroll
        for (int t = 0; t < 32; ++t) a[t] = p[t >> 2][t & 3];
        #pragma unroll
        for (int m = 16; m >= 1; m >>= 1) {
            const bool hi = (kp & m) != 0;
            #pragma unroll
            for (int i = 0; i < m; ++i) {
                float give = hi ? a[i] : a[i + m];
                float got  = __shfl_xor(give, m, 64);
                a[i] = (hi ? a[i + m] : a[i]) + got;
            }
        }
        g_lds[rb_own * 4 + b_own] = a[0] + bsum;
        __syncthreads();

        // ---- activations + h/c update (wave 0 only) ----
        if (tid < 64) {
            int jj = tid >> 2, b4 = tid & 3;
            float gi = g_lds[(0  + jj) * 4 + b4];
            float gf = g_lds[(16 + jj) * 4 + b4];
            float gg = g_lds[(32 + jj) * 4 + b4];
            float go = g_lds[(48 + jj) * 4 + b4];
            c_reg = fsigm(gf) * c_reg + fsigm(gi) * ftanh(gg);
            float h2 = fsigm(go) * ftanh(c_reg);
            int hu = unit0 + jj;
            _Float16 h16 = (_Float16)h2;
            short hb;
            __builtin_memcpy(&hb, &h16, 2);
            if (!layer) {
                __hip_atomic_store((short*)(H0h + (size_t)((st << 2) + b4) * 512 + hu), hb,
                                   __ATOMIC_RELAXED, __HIP_MEMORY_SCOPE_AGENT);
            } else {
                __hip_atomic_store((short*)(H1h + (size_t)((st << 2) + b4) * 512 + hu), hb,
                                   __ATOMIC_RELAXED, __HIP_MEMORY_SCOPE_AGENT);
                __hip_atomic_store(H1 + ((size_t)(b4 * 64 + st)) * 512 + hu, h2,
                                   __ATOMIC_RELAXED, __HIP_MEMORY_SCOPE_AGENT);
            }
        }
        // release: h-stores are wave-0 write-through agent atomics; drain them
        // (vmcnt(0)), then publish the flag (write-through relaxed store).
        if (tid == 0) {
            asm volatile("s_waitcnt vmcnt(0)" ::: "memory");
            __hip_atomic_store(flags + blk * 16, s + 1, __ATOMIC_RELAXED,
                               __HIP_MEMORY_SCOPE_AGENT);
        }
    }
}

// ---------------------------------------------------------------------------
// small fp32 GEMM: C[m][n] = bias[n] + sum_k A[m][k]*Bt[n][k];  N=K=512.
// 64x64 tile per block; grid.x = (M/64)*8
// ---------------------------------------------------------------------------
__global__ void __launch_bounds__(256) k_gemm_small(
        const float* __restrict__ A, const float* __restrict__ Bt,
        const float* __restrict__ bias, float* __restrict__ C) {
    __shared__ float As[64 * 68];
    __shared__ float Bs[64 * 68];
    int bn = blockIdx.x & 7;
    int bm = blockIdx.x >> 3;
    int m0 = bm * 64, n0 = bn * 64;
    int tid = threadIdx.x;
    int tx = tid & 15, ty = tid >> 4;
    float acc[4][4] = {};
    for (int k0 = 0; k0 < 512; k0 += 64) {
        __syncthreads();
        #pragma unroll
        for (int i = 0; i < 4; ++i) {
            int fid = i * 256 + tid;
            int rr = fid >> 4, c4 = (fid & 15) * 4;
            *(float4*)(As + rr * 68 + c4) = *(const float4*)(A + (size_t)(m0 + rr) * 512 + k0 + c4);
            *(float4*)(Bs + rr * 68 + c4) = *(const float4*)(Bt + (size_t)(n0 + rr) * 512 + k0 + c4);
        }
        __syncthreads();
        #pragma unroll 4
        for (int kk = 0; kk < 64; kk += 4) {
            float4 a4[4], b4[4];
            #pragma unroll
            for (int ii = 0; ii < 4; ++ii) a4[ii] = *(const float4*)(As + (ty + ii * 16) * 68 + kk);
            #pragma unroll
            for (int jjx = 0; jjx < 4; ++jjx) b4[jjx] = *(const float4*)(Bs + (tx + jjx * 16) * 68 + kk);
            #pragma unroll
            for (int ii = 0; ii < 4; ++ii)
                #pragma unroll
                for (int jjx = 0; jjx < 4; ++jjx)
                    acc[ii][jjx] += a4[ii].x * b4[jjx].x + a4[ii].y * b4[jjx].y +
                                    a4[ii].z * b4[jjx].z + a4[ii].w * b4[jjx].w;
        }
    }
    #pragma unroll
    for (int ii = 0; ii < 4; ++ii) {
        int m = m0 + ty + ii * 16;
        #pragma unroll
        for (int jjx = 0; jjx < 4; ++jjx) {
            int n = n0 + tx + jjx * 16;
            float v = acc[ii][jjx] + (bias ? bias[n] : 0.f);
            C[(size_t)m * 512 + n] = v;
        }
    }
}

// ---------------------------------------------------------------------------
// joint: out[m][n] = b_out[n] + sum_k tanh(henc[b,t,k]+hdec[b,u,k]) * Wo[n][k]
// m = b*16384 + t*64 + u; M=65536, N=1024, K=512.
// 128x128 tile, BK=64, f16 MFMA 16x16x32, 4 waves 2x2, 4x4 accs each.
// ---------------------------------------------------------------------------
__global__ void __launch_bounds__(256) k_joint(
        const float* __restrict__ henc, const float* __restrict__ hdec,
        const _Float16* __restrict__ Wo, const float* __restrict__ b_out,
        float* __restrict__ out) {
    __shared__ _Float16 As[128 * 72];
    __shared__ _Float16 Bs[128 * 72];

    const int bn = blockIdx.x & 7;
    const int bm = blockIdx.x >> 3;
    const int m0 = bm * 128, n0 = bn * 128;
    const int b  = m0 >> 14;
    const int t0 = (m0 & 16383) >> 6;

    const int tid  = threadIdx.x;
    const int wave = tid >> 6, lane = tid & 63;
    const int wm = wave >> 1, wn = wave & 1;
    const int l16 = lane & 15, quad = lane >> 4;

    const int r_gen = tid >> 1;
    const int half  = tid & 1;
    const int tg = r_gen >> 6, ug = r_gen & 63;
    const float* he_row = henc + ((size_t)(b * 256 + t0 + tg)) * 512 + half * 32;
    const float* hd_row = hdec + ((size_t)(b * 64 + ug)) * 512 + half * 32;
    _Float16* As_row = As + r_gen * 72 + half * 32;

    f32x4 acc[4][4];
    #pragma unroll
    for (int i = 0; i < 4; ++i)
        #pragma unroll
        for (int jx = 0; jx < 4; ++jx) acc[i][jx] = f32x4{0.f, 0.f, 0.f, 0.f};

    for (int kit = 0; kit < 8; ++kit) {
        const int k0 = kit * 64;
        __syncthreads();
        #pragma unroll
        for (int i2 = 0; i2 < 4; ++i2) {
            float4 a  = *(const float4*)(he_row + k0 + i2 * 8);
            float4 c  = *(const float4*)(hd_row + k0 + i2 * 8);
            float4 a2 = *(const float4*)(he_row + k0 + i2 * 8 + 4);
            float4 c2 = *(const float4*)(hd_row + k0 + i2 * 8 + 4);
            f16x8 z8;
            z8[0] = (_Float16)ftanh(a.x + c.x);
            z8[1] = (_Float16)ftanh(a.y + c.y);
            z8[2] = (_Float16)ftanh(a.z + c.z);
            z8[3] = (_Float16)ftanh(a.w + c.w);
            z8[4] = (_Float16)ftanh(a2.x + c2.x);
            z8[5] = (_Float16)ftanh(a2.y + c2.y);
            z8[6] = (_Float16)ftanh(a2.z + c2.z);
            z8[7] = (_Float16)ftanh(a2.w + c2.w);
            *(f16x8*)(As_row + i2 * 8) = z8;
        }
        #pragma unroll
        for (int j2 = 0; j2 < 4; ++j2) {
            int q = j2 * 256 + tid;
            int rr = q >> 3, c8 = q & 7;
            f16x8 w = *(const f16x8*)(Wo + (size_t)(n0 + rr) * 512 + k0 + c8 * 8);
            *(f16x8*)(Bs + rr * 72 + c8 * 8) = w;
        }
        __syncthreads();
        #pragma unroll
        for (int kk = 0; kk < 64; kk += 32) {
            f16x8 af[4], bfv[4];
            #pragma unroll
            for (int i = 0; i < 4; ++i)
                af[i] = *(const f16x8*)(As + (wm * 64 + i * 16 + l16) * 72 + kk + quad * 8);
            #pragma unroll
            for (int jx = 0; jx < 4; ++jx)
                bfv[jx] = *(const f16x8*)(Bs + (wn * 64 + jx * 16 + l16) * 72 + kk + quad * 8);
            #pragma unroll
            for (int i = 0; i < 4; ++i)
                #pragma unroll
                for (int jx = 0; jx < 4; ++jx)
                    acc[i][jx] = __builtin_amdgcn_mfma_f32_16x16x32_f16(af[i], bfv[jx], acc[i][jx], 0, 0, 0);
        }
    }
    #pragma unroll
    for (int i = 0; i < 4; ++i) {
        int mrow = m0 + wm * 64 + i * 16 + quad * 4;
        #pragma unroll
        for (int jx = 0; jx < 4; ++jx) {
            int col = n0 + wn * 64 + jx * 16 + l16;
            float bo = b_out[col];
            float* po = out + (size_t)mrow * 1024 + col;
            po[0]    = acc[i][jx][0] + bo;
            po[1024] = acc[i][jx][1] + bo;
            po[2048] = acc[i][jx][2] + bo;
            po[3072] = acc[i][jx][3] + bo;
        }
    }
}

// ---------------------------------------------------------------------------
extern "C" void kernel_launch(void* const* d_in, const int* in_sizes, int n_in,
                              void* d_out, int out_size, void* d_ws, size_t ws_size,
                              hipStream_t stream) {
    const float* hs    = (const float*)d_in[0];
    const int*   ys    = (const int*)d_in[2];
    const float* embed = (const float*)d_in[3];
    const float* wih0  = (const float*)d_in[4];
    const float* whh0  = (const float*)d_in[5];
    const float* bih0  = (const float*)d_in[6];
    const float* bhh0  = (const float*)d_in[7];
    const float* wih1  = (const float*)d_in[8];
    const float* whh1  = (const float*)d_in[9];
    const float* bih1  = (const float*)d_in[10];
    const float* bhh1  = (const float*)d_in[11];
    const float* wenc  = (const float*)d_in[12];
    const float* benc  = (const float*)d_in[13];
    const float* wdec  = (const float*)d_in[14];
    const float* wout  = (const float*)d_in[15];
    const float* bout  = (const float*)d_in[16];
    float* out = (float*)d_out;

    char* ws = (char*)d_ws;
    _Float16* WF     = (_Float16*)(ws);                               // 9 MB
    _Float16* Ebuf16 = (_Float16*)(ws + 9u  * 1024 * 1024);           // 256 KB
    _Float16* H0h    = (_Float16*)(ws + 9u  * 1024 * 1024 + 512u * 1024); // 256 KB f16
    _Float16* H1h    = (_Float16*)(ws + 9u  * 1024 * 1024 + 768u * 1024); // 256 KB f16
    float* H1    = (float*)(ws + 10u * 1024 * 1024);                  // 512 KB
    float* henc  = (float*)(ws + 10u * 1024 * 1024 + 512u * 1024);    // 2 MB
    float* hdec  = (float*)(ws + 12u * 1024 * 1024 + 512u * 1024);    // 512 KB
    int*   flags = (int*)  (ws + 13u * 1024 * 1024);                  // 4 KB

    hipMemsetAsync(flags, 0, 64 * 16 * sizeof(int), stream);
    k_prep_f16<<<2048, 256, 0, stream>>>(wih0, whh0, wih1, whh1, wout, WF, 4718592);
    k_embed<<<256, 256, 0, stream>>>(embed, ys, Ebuf16);
    k_lstm<<<64, 256, 0, stream>>>(WF, bih0, bhh0, bih1, bhh1, Ebuf16, H0h, H1h, H1, flags);
    k_gemm_small<<<128, 256, 0, stream>>>(hs, wenc, benc, henc);      // M=1024
    k_gemm_small<<<32, 256, 0, stream>>>(H1, wdec, nullptr, hdec);    // M=256
    k_joint<<<4096, 256, 0, stream>>>(henc, hdec, WF + (4u << 20), bout, out);
}

// Round 4
// 748.280 us; speedup vs baseline: 2.1793x; 2.1793x over previous
//
#include <hip/hip_runtime.h>
#include <hip/hip_bf16.h>
#include <cstdint>
#include <cstddef>

#define DEVINL __device__ __forceinline__

typedef _Float16 f16x8 __attribute__((ext_vector_type(8)));
typedef _Float16 f16x2 __attribute__((ext_vector_type(2)));
typedef float    f32x4 __attribute__((ext_vector_type(4)));

#define SENT 0xFFFFFFFFFFFFFFFFull

// B=4, T=256, U=64, E=H=J=512, O=1024, gate rows 2048

DEVINL float fsigm(float x) {
    float e = __expf(-x);
    return __builtin_amdgcn_rcpf(1.f + e);
}
DEVINL float ftanh(float x) {
    float e = __expf(2.f * x);
    return 1.f - 2.f * __builtin_amdgcn_rcpf(e + 1.f);
}

DEVINL float dot8(f16x8 w, f16x8 x, float acc) {
    f16x2 w0{w[0], w[1]}, w1{w[2], w[3]}, w2{w[4], w[5]}, w3{w[6], w[7]};
    f16x2 x0{x[0], x[1]}, x1{x[2], x[3]}, x2{x[4], x[5]}, x3{x[6], x[7]};
    acc = __builtin_amdgcn_fdot2(w0, x0, acc, false);
    acc = __builtin_amdgcn_fdot2(w1, x1, acc, false);
    acc = __builtin_amdgcn_fdot2(w2, x2, acc, false);
    acc = __builtin_amdgcn_fdot2(w3, x3, acc, false);
    return acc;
}

// Sentinel-poll one history slot (4 batch rows x 2 chunks of 16B for this
// lane's kp). Data arrives IN the poll: exits holding valid payload.
// H is written only via packed 8B agent-atomic stores; 0xFFFF f16 bit
// pattern (NaN) never occurs in finite h values.
DEVINL void pollrows(const _Float16* __restrict__ H, int slot, int kp,
                     f16x8 out[4][2]) {
    const uint64_t* base = (const uint64_t*)H + (size_t)slot * 512;
    uint64_t w[16];
    for (;;) {
        bool bad = false;
        #pragma unroll
        for (int b = 0; b < 4; ++b) {
            const uint64_t* rp = base + b * 128 + kp * 2;
            w[b * 4 + 0] = __hip_atomic_load(rp,      __ATOMIC_RELAXED, __HIP_MEMORY_SCOPE_AGENT);
            w[b * 4 + 1] = __hip_atomic_load(rp + 1,  __ATOMIC_RELAXED, __HIP_MEMORY_SCOPE_AGENT);
            w[b * 4 + 2] = __hip_atomic_load(rp + 64, __ATOMIC_RELAXED, __HIP_MEMORY_SCOPE_AGENT);
            w[b * 4 + 3] = __hip_atomic_load(rp + 65, __ATOMIC_RELAXED, __HIP_MEMORY_SCOPE_AGENT);
        }
        #pragma unroll
        for (int i = 0; i < 16; ++i) bad |= (w[i] == SENT);
        if (!bad) break;
        __builtin_amdgcn_s_sleep(1);
    }
    #pragma unroll
    for (int b = 0; b < 4; ++b) {
        union { uint64_t u[2]; f16x8 v; } u0, u1;
        u0.u[0] = w[b * 4 + 0]; u0.u[1] = w[b * 4 + 1];
        u1.u[0] = w[b * 4 + 2]; u1.u[1] = w[b * 4 + 3];
        out[b][0] = u0.v;
        out[b][1] = u1.v;
    }
}

// ---------------------------------------------------------------------------
// prep: cast LSTM weights + W_out to f16
// dst layout (elements): [Wih0 1M | Whh0 1M | Wih1 1M | Whh1 1M | Wout 0.5M]
// ---------------------------------------------------------------------------
__global__ void k_prep_f16(const float* __restrict__ wih0, const float* __restrict__ whh0,
                           const float* __restrict__ wih1, const float* __restrict__ whh1,
                           const float* __restrict__ wout, _Float16* __restrict__ dst, int total) {
    int stride = gridDim.x * blockDim.x;
    for (int i = blockIdx.x * blockDim.x + threadIdx.x; i < total; i += stride) {
        const float* src; int off;
        if      (i < (1 << 20)) { src = wih0; off = i; }
        else if (i < (2 << 20)) { src = whh0; off = i - (1 << 20); }
        else if (i < (3 << 20)) { src = wih1; off = i - (2 << 20); }
        else if (i < (4 << 20)) { src = whh1; off = i - (3 << 20); }
        else                    { src = wout; off = i - (4 << 20); }
        dst[i] = (_Float16)src[off];
    }
}

// ---------------------------------------------------------------------------
// embedding gather (f16 output): Ebuf[(u*4+b)*512 + e] = embed[ys_in[b][u]][e]
// ---------------------------------------------------------------------------
__global__ void k_embed(const float* __restrict__ embed, const int* __restrict__ ys,
                        _Float16* __restrict__ Ebuf) {
    int bu = blockIdx.x;           // 0..255
    int b = bu >> 6, u = bu & 63;
    int tok = (u == 0) ? 0 : ys[b * 63 + (u - 1)];
    const float* src = embed + (size_t)tok * 512;
    _Float16* dst = Ebuf + ((size_t)(u * 4 + b)) * 512;
    int t2 = threadIdx.x * 2;
    float2 v = *(const float2*)(src + t2);
    dst[t2]     = (_Float16)v.x;
    dst[t2 + 1] = (_Float16)v.y;
}

// ---------------------------------------------------------------------------
// persistent 2-layer LSTM. 64 blocks x 256 threads.
// blocks 0..31: layer0, 32..63: layer1 (lagging one round).
// Block owns 16 hidden units -> 64 gate rows x 4 batches.
//
// v5: NO FLAGS. The h history buffers are pre-poisoned with 0xFF; consumers
// sentinel-poll exactly the 8B payload words they need (relaxed agent
// atomics, LLC-coherent). The poll exits holding the data -> the handoff is
// one store-to-LLC latency + poll period, with no vmcnt-drain + flag-store
// + flag-poll serialization. Producers pack 4 f16 into one 8B atomic store
// (3 shfl_down), so each polled word turns valid with a single store.
// Waves self-synchronize round-to-round: every lane's poll set includes
// words its own wave0 produced last round; an end-of-round barrier guards
// the g_lds reuse.
// ---------------------------------------------------------------------------
__global__ void __launch_bounds__(256, 1) k_lstm(
        const _Float16* __restrict__ WF,
        const float* __restrict__ bih0, const float* __restrict__ bhh0,
        const float* __restrict__ bih1, const float* __restrict__ bhh1,
        const _Float16* __restrict__ Ebuf,
        _Float16* __restrict__ H0h, _Float16* __restrict__ H1h,
        float* __restrict__ H1) {
    const int blk   = blockIdx.x;
    const int layer = blk >> 5;
    const int ublk  = blk & 31;
    const int unit0 = ublk * 16;
    const int tid   = threadIdx.x;
    const int rg    = tid >> 5;          // 0..7 : row group (8 rows)
    const int kp    = tid & 31;          // 0..31: k phase

    // cell owned after reduce-scatter
    const int rb_own   = rg * 8 + (kp >> 2);                 // 0..63
    const int b_own    = kp & 3;
    const int grow_own = ((rb_own >> 4) << 9) + unit0 + (rb_own & 15);

    const _Float16* WihL = WF + (size_t)(layer ? (2u << 20) : 0u);
    const _Float16* WhhL = WF + (size_t)(layer ? (3u << 20) : (1u << 20));

    // ---- persistent weights in VGPRs ----
    f16x8 wA[8][2];   // Wih rows
    f16x8 wB[8][2];   // Whh rows
    #pragma unroll
    for (int r = 0; r < 8; ++r) {
        int rb = rg * 8 + r;
        int grow = ((rb >> 4) << 9) + unit0 + (rb & 15);
        const _Float16* irow = WihL + (size_t)grow * 512;
        const _Float16* hrow = WhhL + (size_t)grow * 512;
        wA[r][0] = *(const f16x8*)(irow + kp * 8);
        wA[r][1] = *(const f16x8*)(irow + 256 + kp * 8);
        wB[r][0] = *(const f16x8*)(hrow + kp * 8);
        wB[r][1] = *(const f16x8*)(hrow + 256 + kp * 8);
    }
    const float* biL = layer ? bih1 : bih0;
    const float* bhL = layer ? bhh1 : bhh0;
    const float bsum = biL[grow_own] + bhL[grow_own];

    __shared__ float g_lds[64 * 4];      // gates [rb][b]

    float c_reg = 0.f;
    const int c0 = kp * 8;               // f16 elem offset, chunk 0
    const int c1 = 256 + kp * 8;         // f16 elem offset, chunk 1
    const int s_lo = layer ? 1 : 0;
    const int s_hi = layer ? 64 : 63;

    for (int s = s_lo; s <= s_hi; ++s) {
        const int st = s - s_lo;         // L0: st=s ; L1: st=s-1

        float p[8][4];
        #pragma unroll
        for (int r = 0; r < 8; ++r)
            #pragma unroll
            for (int b = 0; b < 4; ++b) p[r][b] = 0.f;

        if (!layer) {
            // ---- x slices from Ebuf (cached, static) + ih dots first ----
            #pragma unroll
            for (int b = 0; b < 4; ++b) {
                const _Float16* er = Ebuf + ((size_t)(st * 4 + b)) * 512;
                f16x8 x0 = *(const f16x8*)(er + c0);
                f16x8 x1 = *(const f16x8*)(er + c1);
                #pragma unroll
                for (int r = 0; r < 8; ++r) {
                    p[r][b] = dot8(wA[r][0], x0, p[r][b]);
                    p[r][b] = dot8(wA[r][1], x1, p[r][b]);
                }
            }
            if (st > 0) {
                f16x8 hv[4][2];
                pollrows(H0h, st - 1, kp, hv);       // wait directly on payload
                #pragma unroll
                for (int b = 0; b < 4; ++b)
                    #pragma unroll
                    for (int r = 0; r < 8; ++r) {
                        p[r][b] = dot8(wB[r][0], hv[b][0], p[r][b]);
                        p[r][b] = dot8(wB[r][1], hv[b][1], p[r][b]);
                    }
            }
        } else {
            // ---- x = h0[st]: poll payload, then ih dots ----
            f16x8 xv[4][2];
            pollrows(H0h, st, kp, xv);
            #pragma unroll
            for (int b = 0; b < 4; ++b)
                #pragma unroll
                for (int r = 0; r < 8; ++r) {
                    p[r][b] = dot8(wA[r][0], xv[b][0], p[r][b]);
                    p[r][b] = dot8(wA[r][1], xv[b][1], p[r][b]);
                }
            if (st > 0) {
                f16x8 hv[4][2];
                pollrows(H1h, st - 1, kp, hv);       // own-layer, usually ready
                #pragma unroll
                for (int b = 0; b < 4; ++b)
                    #pragma unroll
                    for (int r = 0; r < 8; ++r) {
                        p[r][b] = dot8(wB[r][0], hv[b][0], p[r][b]);
                        p[r][b] = dot8(wB[r][1], hv[b][1], p[r][b]);
                    }
            }
        }

        // ---- butterfly reduce-scatter over 32 kp lanes: lane kp owns t=kp ----
        float a[32];
        #pragma unroll
        for (int t = 0; t < 32; ++t) a[t] = p[t >> 2][t & 3];
        #pragma unroll
        for (int m = 16; m >= 1; m >>= 1) {
            const bool hi = (kp & m) != 0;
            #pragma unroll
            for (int i = 0; i < m; ++i) {
                float give = hi ? a[i] : a[i + m];
                float got  = __shfl_xor(give, m, 64);
                a[i] = (hi ? a[i + m] : a[i]) + got;
            }
        }
        g_lds[rb_own * 4 + b_own] = a[0] + bsum;
        __syncthreads();

        // ---- activations + h/c update + packed publish (wave 0 only) ----
        if (tid < 64) {
            int jj = tid >> 2, b4 = tid & 3;
            float gi = g_lds[(0  + jj) * 4 + b4];
            float gf = g_lds[(16 + jj) * 4 + b4];
            float gg = g_lds[(32 + jj) * 4 + b4];
            float go = g_lds[(48 + jj) * 4 + b4];
            c_reg = fsigm(gf) * c_reg + fsigm(gi) * ftanh(gg);
            float h2 = fsigm(go) * ftanh(c_reg);
            _Float16 h16 = (_Float16)h2;
            unsigned short hb;
            __builtin_memcpy(&hb, &h16, 2);
            int hv0 = (int)hb;
            // gather units jj+1, jj+2, jj+3 (same b4) into lanes jj%4==0
            int hv1 = __shfl_down(hv0, 4, 64);
            int hv2 = __shfl_down(hv0, 8, 64);
            int hv3 = __shfl_down(hv0, 12, 64);
            if ((jj & 3) == 0) {
                uint64_t pk = (uint64_t)(hv0 & 0xFFFF)
                            | ((uint64_t)(hv1 & 0xFFFF) << 16)
                            | ((uint64_t)(hv2 & 0xFFFF) << 32)
                            | ((uint64_t)(hv3 & 0xFFFF) << 48);
                _Float16* dst = (layer ? H1h : H0h) + (size_t)((st << 2) + b4) * 512 + unit0 + jj;
                __hip_atomic_store((uint64_t*)dst, pk,
                                   __ATOMIC_RELAXED, __HIP_MEMORY_SCOPE_AGENT);
            }
            if (layer) {
                int hu = unit0 + jj;
                __hip_atomic_store(H1 + ((size_t)(b4 * 64 + st)) * 512 + hu, h2,
                                   __ATOMIC_RELAXED, __HIP_MEMORY_SCOPE_AGENT);
            }
        }
        __syncthreads();   // g_lds reuse guard for next round
    }
}

// ---------------------------------------------------------------------------
// small fp32 GEMM: C[m][n] = bias[n] + sum_k A[m][k]*Bt[n][k];  N=K=512.
// 64x64 tile per block; grid.x = (M/64)*8
// ---------------------------------------------------------------------------
__global__ void __launch_bounds__(256) k_gemm_small(
        const float* __restrict__ A, const float* __restrict__ Bt,
        const float* __restrict__ bias, float* __restrict__ C) {
    __shared__ float As[64 * 68];
    __shared__ float Bs[64 * 68];
    int bn = blockIdx.x & 7;
    int bm = blockIdx.x >> 3;
    int m0 = bm * 64, n0 = bn * 64;
    int tid = threadIdx.x;
    int tx = tid & 15, ty = tid >> 4;
    float acc[4][4] = {};
    for (int k0 = 0; k0 < 512; k0 += 64) {
        __syncthreads();
        #pragma unroll
        for (int i = 0; i < 4; ++i) {
            int fid = i * 256 + tid;
            int rr = fid >> 4, c4 = (fid & 15) * 4;
            *(float4*)(As + rr * 68 + c4) = *(const float4*)(A + (size_t)(m0 + rr) * 512 + k0 + c4);
            *(float4*)(Bs + rr * 68 + c4) = *(const float4*)(Bt + (size_t)(n0 + rr) * 512 + k0 + c4);
        }
        __syncthreads();
        #pragma unroll 4
        for (int kk = 0; kk < 64; kk += 4) {
            float4 a4[4], b4[4];
            #pragma unroll
            for (int ii = 0; ii < 4; ++ii) a4[ii] = *(const float4*)(As + (ty + ii * 16) * 68 + kk);
            #pragma unroll
            for (int jjx = 0; jjx < 4; ++jjx) b4[jjx] = *(const float4*)(Bs + (tx + jjx * 16) * 68 + kk);
            #pragma unroll
            for (int ii = 0; ii < 4; ++ii)
                #pragma unroll
                for (int jjx = 0; jjx < 4; ++jjx)
                    acc[ii][jjx] += a4[ii].x * b4[jjx].x + a4[ii].y * b4[jjx].y +
                                    a4[ii].z * b4[jjx].z + a4[ii].w * b4[jjx].w;
        }
    }
    #pragma unroll
    for (int ii = 0; ii < 4; ++ii) {
        int m = m0 + ty + ii * 16;
        #pragma unroll
        for (int jjx = 0; jjx < 4; ++jjx) {
            int n = n0 + tx + jjx * 16;
            float v = acc[ii][jjx] + (bias ? bias[n] : 0.f);
            C[(size_t)m * 512 + n] = v;
        }
    }
}

// ---------------------------------------------------------------------------
// joint: out[m][n] = b_out[n] + sum_k tanh(henc[b,t,k]+hdec[b,u,k]) * Wo[n][k]
// m = b*16384 + t*64 + u; M=65536, N=1024, K=512.
// 128x128 tile, BK=64, f16 MFMA 16x16x32, 4 waves 2x2, 4x4 accs each.
// ---------------------------------------------------------------------------
__global__ void __launch_bounds__(256) k_joint(
        const float* __restrict__ henc, const float* __restrict__ hdec,
        const _Float16* __restrict__ Wo, const float* __restrict__ b_out,
        float* __restrict__ out) {
    __shared__ _Float16 As[128 * 72];
    __shared__ _Float16 Bs[128 * 72];

    const int bn = blockIdx.x & 7;
    const int bm = blockIdx.x >> 3;
    const int m0 = bm * 128, n0 = bn * 128;
    const int b  = m0 >> 14;
    const int t0 = (m0 & 16383) >> 6;

    const int tid  = threadIdx.x;
    const int wave = tid >> 6, lane = tid & 63;
    const int wm = wave >> 1, wn = wave & 1;
    const int l16 = lane & 15, quad = lane >> 4;

    const int r_gen = tid >> 1;
    const int half  = tid & 1;
    const int tg = r_gen >> 6, ug = r_gen & 63;
    const float* he_row = henc + ((size_t)(b * 256 + t0 + tg)) * 512 + half * 32;
    const float* hd_row = hdec + ((size_t)(b * 64 + ug)) * 512 + half * 32;
    _Float16* As_row = As + r_gen * 72 + half * 32;

    f32x4 acc[4][4];
    #pragma unroll
    for (int i = 0; i < 4; ++i)
        #pragma unroll
        for (int jx = 0; jx < 4; ++jx) acc[i][jx] = f32x4{0.f, 0.f, 0.f, 0.f};

    for (int kit = 0; kit < 8; ++kit) {
        const int k0 = kit * 64;
        __syncthreads();
        #pragma unroll
        for (int i2 = 0; i2 < 4; ++i2) {
            float4 a  = *(const float4*)(he_row + k0 + i2 * 8);
            float4 c  = *(const float4*)(hd_row + k0 + i2 * 8);
            float4 a2 = *(const float4*)(he_row + k0 + i2 * 8 + 4);
            float4 c2 = *(const float4*)(hd_row + k0 + i2 * 8 + 4);
            f16x8 z8;
            z8[0] = (_Float16)ftanh(a.x + c.x);
            z8[1] = (_Float16)ftanh(a.y + c.y);
            z8[2] = (_Float16)ftanh(a.z + c.z);
            z8[3] = (_Float16)ftanh(a.w + c.w);
            z8[4] = (_Float16)ftanh(a2.x + c2.x);
            z8[5] = (_Float16)ftanh(a2.y + c2.y);
            z8[6] = (_Float16)ftanh(a2.z + c2.z);
            z8[7] = (_Float16)ftanh(a2.w + c2.w);
            *(f16x8*)(As_row + i2 * 8) = z8;
        }
        #pragma unroll
        for (int j2 = 0; j2 < 4; ++j2) {
            int q = j2 * 256 + tid;
            int rr = q >> 3, c8 = q & 7;
            f16x8 w = *(const f16x8*)(Wo + (size_t)(n0 + rr) * 512 + k0 + c8 * 8);
            *(f16x8*)(Bs + rr * 72 + c8 * 8) = w;
        }
        __syncthreads();
        #pragma unroll
        for (int kk = 0; kk < 64; kk += 32) {
            f16x8 af[4], bfv[4];
            #pragma unroll
            for (int i = 0; i < 4; ++i)
                af[i] = *(const f16x8*)(As + (wm * 64 + i * 16 + l16) * 72 + kk + quad * 8);
            #pragma unroll
            for (int jx = 0; jx < 4; ++jx)
                bfv[jx] = *(const f16x8*)(Bs + (wn * 64 + jx * 16 + l16) * 72 + kk + quad * 8);
            #pragma unroll
            for (int i = 0; i < 4; ++i)
                #pragma unroll
                for (int jx = 0; jx < 4; ++jx)
                    acc[i][jx] = __builtin_amdgcn_mfma_f32_16x16x32_f16(af[i], bfv[jx], acc[i][jx], 0, 0, 0);
        }
    }
    #pragma unroll
    for (int i = 0; i < 4; ++i) {
        int mrow = m0 + wm * 64 + i * 16 + quad * 4;
        #pragma unroll
        for (int jx = 0; jx < 4; ++jx) {
            int col = n0 + wn * 64 + jx * 16 + l16;
            float bo = b_out[col];
            float* po = out + (size_t)mrow * 1024 + col;
            po[0]    = acc[i][jx][0] + bo;
            po[1024] = acc[i][jx][1] + bo;
            po[2048] = acc[i][jx][2] + bo;
            po[3072] = acc[i][jx][3] + bo;
        }
    }
}

// ---------------------------------------------------------------------------
extern "C" void kernel_launch(void* const* d_in, const int* in_sizes, int n_in,
                              void* d_out, int out_size, void* d_ws, size_t ws_size,
                              hipStream_t stream) {
    const float* hs    = (const float*)d_in[0];
    const int*   ys    = (const int*)d_in[2];
    const float* embed = (const float*)d_in[3];
    const float* wih0  = (const float*)d_in[4];
    const float* whh0  = (const float*)d_in[5];
    const float* bih0  = (const float*)d_in[6];
    const float* bhh0  = (const float*)d_in[7];
    const float* wih1  = (const float*)d_in[8];
    const float* whh1  = (const float*)d_in[9];
    const float* bih1  = (const float*)d_in[10];
    const float* bhh1  = (const float*)d_in[11];
    const float* wenc  = (const float*)d_in[12];
    const float* benc  = (const float*)d_in[13];
    const float* wdec  = (const float*)d_in[14];
    const float* wout  = (const float*)d_in[15];
    const float* bout  = (const float*)d_in[16];
    float* out = (float*)d_out;

    char* ws = (char*)d_ws;
    _Float16* WF     = (_Float16*)(ws);                               // 9 MB
    _Float16* Ebuf16 = (_Float16*)(ws + 9u  * 1024 * 1024);           // 256 KB
    _Float16* H0h    = (_Float16*)(ws + 9u  * 1024 * 1024 + 512u * 1024); // 256 KB f16
    _Float16* H1h    = (_Float16*)(ws + 9u  * 1024 * 1024 + 768u * 1024); // 256 KB f16
    float* H1    = (float*)(ws + 10u * 1024 * 1024);                  // 512 KB
    float* henc  = (float*)(ws + 10u * 1024 * 1024 + 512u * 1024);    // 2 MB
    float* hdec  = (float*)(ws + 12u * 1024 * 1024 + 512u * 1024);    // 512 KB

    // poison h history with f16-NaN sentinel (0xFFFF); finite h never matches
    hipMemsetAsync(ws + 9u * 1024 * 1024 + 512u * 1024, 0xFF, 512u * 1024, stream);
    k_prep_f16<<<2048, 256, 0, stream>>>(wih0, whh0, wih1, whh1, wout, WF, 4718592);
    k_embed<<<256, 256, 0, stream>>>(embed, ys, Ebuf16);
    k_lstm<<<64, 256, 0, stream>>>(WF, bih0, bhh0, bih1, bhh1, Ebuf16, H0h, H1h, H1);
    k_gemm_small<<<128, 256, 0, stream>>>(hs, wenc, benc, henc);      // M=1024
    k_gemm_small<<<32, 256, 0, stream>>>(H1, wdec, nullptr, hdec);    // M=256
    k_joint<<<4096, 256, 0, stream>>>(henc, hdec, WF + (4u << 20), bout, out);
}

// Round 5
// 688.795 us; speedup vs baseline: 2.3675x; 1.0864x over previous
//
#include <hip/hip_runtime.h>
#include <hip/hip_bf16.h>
#include <cstdint>
#include <cstddef>

#define DEVINL __device__ __forceinline__

typedef _Float16 f16x8 __attribute__((ext_vector_type(8)));
typedef _Float16 f16x2 __attribute__((ext_vector_type(2)));
typedef float    f32x4 __attribute__((ext_vector_type(4)));

#define SENT 0xFFFFFFFFFFFFFFFFull

// B=4, T=256, U=64, E=H=J=512, O=1024, gate rows 2048

DEVINL float fsigm(float x) {
    float e = __expf(-x);
    return __builtin_amdgcn_rcpf(1.f + e);
}
DEVINL float ftanh(float x) {
    float e = __expf(2.f * x);
    return 1.f - 2.f * __builtin_amdgcn_rcpf(e + 1.f);
}

DEVINL float dot8(f16x8 w, f16x8 x, float acc) {
    f16x2 w0{w[0], w[1]}, w1{w[2], w[3]}, w2{w[4], w[5]}, w3{w[6], w[7]};
    f16x2 x0{x[0], x[1]}, x1{x[2], x[3]}, x2{x[4], x[5]}, x3{x[6], x[7]};
    acc = __builtin_amdgcn_fdot2(w0, x0, acc, false);
    acc = __builtin_amdgcn_fdot2(w1, x1, acc, false);
    acc = __builtin_amdgcn_fdot2(w2, x2, acc, false);
    acc = __builtin_amdgcn_fdot2(w3, x3, acc, false);
    return acc;
}

// Sentinel-poll one history slot (4 batch rows x 2 chunks of 16B for this
// lane's kp). Data arrives IN the poll: exits holding valid payload.
DEVINL void pollrows(const _Float16* __restrict__ H, int slot, int kp,
                     f16x8 out[4][2]) {
    const uint64_t* base = (const uint64_t*)H + (size_t)slot * 512;
    uint64_t w[16];
    for (;;) {
        bool bad = false;
        #pragma unroll
        for (int b = 0; b < 4; ++b) {
            const uint64_t* rp = base + b * 128 + kp * 2;
            w[b * 4 + 0] = __hip_atomic_load(rp,      __ATOMIC_RELAXED, __HIP_MEMORY_SCOPE_AGENT);
            w[b * 4 + 1] = __hip_atomic_load(rp + 1,  __ATOMIC_RELAXED, __HIP_MEMORY_SCOPE_AGENT);
            w[b * 4 + 2] = __hip_atomic_load(rp + 64, __ATOMIC_RELAXED, __HIP_MEMORY_SCOPE_AGENT);
            w[b * 4 + 3] = __hip_atomic_load(rp + 65, __ATOMIC_RELAXED, __HIP_MEMORY_SCOPE_AGENT);
        }
        #pragma unroll
        for (int i = 0; i < 16; ++i) bad |= (w[i] == SENT);
        if (!bad) break;
        __builtin_amdgcn_s_sleep(1);
    }
    #pragma unroll
    for (int b = 0; b < 4; ++b) {
        union { uint64_t u[2]; f16x8 v; } u0, u1;
        u0.u[0] = w[b * 4 + 0]; u0.u[1] = w[b * 4 + 1];
        u1.u[0] = w[b * 4 + 2]; u1.u[1] = w[b * 4 + 3];
        out[b][0] = u0.v;
        out[b][1] = u1.v;
    }
}

// ---------------------------------------------------------------------------
// prep: cast LSTM weights + W_out to f16
// ---------------------------------------------------------------------------
__global__ void k_prep_f16(const float* __restrict__ wih0, const float* __restrict__ whh0,
                           const float* __restrict__ wih1, const float* __restrict__ whh1,
                           const float* __restrict__ wout, _Float16* __restrict__ dst, int total) {
    int stride = gridDim.x * blockDim.x;
    for (int i = blockIdx.x * blockDim.x + threadIdx.x; i < total; i += stride) {
        const float* src; int off;
        if      (i < (1 << 20)) { src = wih0; off = i; }
        else if (i < (2 << 20)) { src = whh0; off = i - (1 << 20); }
        else if (i < (3 << 20)) { src = wih1; off = i - (2 << 20); }
        else if (i < (4 << 20)) { src = whh1; off = i - (3 << 20); }
        else                    { src = wout; off = i - (4 << 20); }
        dst[i] = (_Float16)src[off];
    }
}

// ---------------------------------------------------------------------------
// embedding gather (f16 output): Ebuf[(u*4+b)*512 + e] = embed[ys_in[b][u]][e]
// ---------------------------------------------------------------------------
__global__ void k_embed(const float* __restrict__ embed, const int* __restrict__ ys,
                        _Float16* __restrict__ Ebuf) {
    int bu = blockIdx.x;           // 0..255
    int b = bu >> 6, u = bu & 63;
    int tok = (u == 0) ? 0 : ys[b * 63 + (u - 1)];
    const float* src = embed + (size_t)tok * 512;
    _Float16* dst = Ebuf + ((size_t)(u * 4 + b)) * 512;
    int t2 = threadIdx.x * 2;
    float2 v = *(const float2*)(src + t2);
    dst[t2]     = (_Float16)v.x;
    dst[t2 + 1] = (_Float16)v.y;
}

// ---------------------------------------------------------------------------
// small fp32 GEMM body: C[m][n] = bias[n] + sum_k A[m][k]*Bt[n][k]; N=K=512.
// 64x64 tile per block-id; used standalone (hdec) and fused (henc).
// ---------------------------------------------------------------------------
DEVINL void gemm_small_body(const float* __restrict__ A, const float* __restrict__ Bt,
                            const float* __restrict__ bias, float* __restrict__ C,
                            int blk) {
    __shared__ float As[64 * 68];
    __shared__ float Bs[64 * 68];
    int bn = blk & 7;
    int bm = blk >> 3;
    int m0 = bm * 64, n0 = bn * 64;
    int tid = threadIdx.x;
    int tx = tid & 15, ty = tid >> 4;
    float acc[4][4] = {};
    for (int k0 = 0; k0 < 512; k0 += 64) {
        __syncthreads();
        #pragma unroll
        for (int i = 0; i < 4; ++i) {
            int fid = i * 256 + tid;
            int rr = fid >> 4, c4 = (fid & 15) * 4;
            *(float4*)(As + rr * 68 + c4) = *(const float4*)(A + (size_t)(m0 + rr) * 512 + k0 + c4);
            *(float4*)(Bs + rr * 68 + c4) = *(const float4*)(Bt + (size_t)(n0 + rr) * 512 + k0 + c4);
        }
        __syncthreads();
        #pragma unroll 4
        for (int kk = 0; kk < 64; kk += 4) {
            float4 a4[4], b4[4];
            #pragma unroll
            for (int ii = 0; ii < 4; ++ii) a4[ii] = *(const float4*)(As + (ty + ii * 16) * 68 + kk);
            #pragma unroll
            for (int jjx = 0; jjx < 4; ++jjx) b4[jjx] = *(const float4*)(Bs + (tx + jjx * 16) * 68 + kk);
            #pragma unroll
            for (int ii = 0; ii < 4; ++ii)
                #pragma unroll
                for (int jjx = 0; jjx < 4; ++jjx)
                    acc[ii][jjx] += a4[ii].x * b4[jjx].x + a4[ii].y * b4[jjx].y +
                                    a4[ii].z * b4[jjx].z + a4[ii].w * b4[jjx].w;
        }
    }
    #pragma unroll
    for (int ii = 0; ii < 4; ++ii) {
        int m = m0 + ty + ii * 16;
        #pragma unroll
        for (int jjx = 0; jjx < 4; ++jjx) {
            int n = n0 + tx + jjx * 16;
            float v = acc[ii][jjx] + (bias ? bias[n] : 0.f);
            C[(size_t)m * 512 + n] = v;
        }
    }
}

__global__ void __launch_bounds__(256) k_gemm_small(
        const float* __restrict__ A, const float* __restrict__ Bt,
        const float* __restrict__ bias, float* __restrict__ C) {
    gemm_small_body(A, Bt, bias, C, blockIdx.x);
}

// ---------------------------------------------------------------------------
// persistent 2-layer LSTM (blocks 0..63) + fused henc-GEMM (blocks 64..191).
// The henc projection (hs @ Wenc^T + benc) is independent of the LSTM, and
// the LSTM only occupies 64 CUs -> run the GEMM on idle CUs concurrently.
//
// LSTM sync = v5 sentinel-poll: h history buffers pre-poisoned 0xFF;
// consumers poll the payload words directly (relaxed agent atomics).
// ---------------------------------------------------------------------------
__global__ void __launch_bounds__(256, 1) k_lstm(
        const _Float16* __restrict__ WF,
        const float* __restrict__ bih0, const float* __restrict__ bhh0,
        const float* __restrict__ bih1, const float* __restrict__ bhh1,
        const _Float16* __restrict__ Ebuf,
        _Float16* __restrict__ H0h, _Float16* __restrict__ H1h,
        float* __restrict__ H1,
        const float* __restrict__ hs, const float* __restrict__ wenc,
        const float* __restrict__ benc, float* __restrict__ henc) {
    if (blockIdx.x >= 64) {
        gemm_small_body(hs, wenc, benc, henc, blockIdx.x - 64);
        return;
    }
    const int blk   = blockIdx.x;
    const int layer = blk >> 5;
    const int ublk  = blk & 31;
    const int unit0 = ublk * 16;
    const int tid   = threadIdx.x;
    const int rg    = tid >> 5;          // 0..7 : row group (8 rows)
    const int kp    = tid & 31;          // 0..31: k phase

    const int rb_own   = rg * 8 + (kp >> 2);                 // 0..63
    const int b_own    = kp & 3;
    const int grow_own = ((rb_own >> 4) << 9) + unit0 + (rb_own & 15);

    const _Float16* WihL = WF + (size_t)(layer ? (2u << 20) : 0u);
    const _Float16* WhhL = WF + (size_t)(layer ? (3u << 20) : (1u << 20));

    // ---- persistent weights in VGPRs ----
    f16x8 wA[8][2];
    f16x8 wB[8][2];
    #pragma unroll
    for (int r = 0; r < 8; ++r) {
        int rb = rg * 8 + r;
        int grow = ((rb >> 4) << 9) + unit0 + (rb & 15);
        const _Float16* irow = WihL + (size_t)grow * 512;
        const _Float16* hrow = WhhL + (size_t)grow * 512;
        wA[r][0] = *(const f16x8*)(irow + kp * 8);
        wA[r][1] = *(const f16x8*)(irow + 256 + kp * 8);
        wB[r][0] = *(const f16x8*)(hrow + kp * 8);
        wB[r][1] = *(const f16x8*)(hrow + 256 + kp * 8);
    }
    const float* biL = layer ? bih1 : bih0;
    const float* bhL = layer ? bhh1 : bhh0;
    const float bsum = biL[grow_own] + bhL[grow_own];

    __shared__ float g_lds[64 * 4];      // gates [rb][b]

    float c_reg = 0.f;
    const int c0 = kp * 8;
    const int c1 = 256 + kp * 8;
    const int s_lo = layer ? 1 : 0;
    const int s_hi = layer ? 64 : 63;

    for (int s = s_lo; s <= s_hi; ++s) {
        const int st = s - s_lo;

        float p[8][4];
        #pragma unroll
        for (int r = 0; r < 8; ++r)
            #pragma unroll
            for (int b = 0; b < 4; ++b) p[r][b] = 0.f;

        if (!layer) {
            #pragma unroll
            for (int b = 0; b < 4; ++b) {
                const _Float16* er = Ebuf + ((size_t)(st * 4 + b)) * 512;
                f16x8 x0 = *(const f16x8*)(er + c0);
                f16x8 x1 = *(const f16x8*)(er + c1);
                #pragma unroll
                for (int r = 0; r < 8; ++r) {
                    p[r][b] = dot8(wA[r][0], x0, p[r][b]);
                    p[r][b] = dot8(wA[r][1], x1, p[r][b]);
                }
            }
            if (st > 0) {
                f16x8 hv[4][2];
                pollrows(H0h, st - 1, kp, hv);
                #pragma unroll
                for (int b = 0; b < 4; ++b)
                    #pragma unroll
                    for (int r = 0; r < 8; ++r) {
                        p[r][b] = dot8(wB[r][0], hv[b][0], p[r][b]);
                        p[r][b] = dot8(wB[r][1], hv[b][1], p[r][b]);
                    }
            }
        } else {
            f16x8 xv[4][2];
            pollrows(H0h, st, kp, xv);
            #pragma unroll
            for (int b = 0; b < 4; ++b)
                #pragma unroll
                for (int r = 0; r < 8; ++r) {
                    p[r][b] = dot8(wA[r][0], xv[b][0], p[r][b]);
                    p[r][b] = dot8(wA[r][1], xv[b][1], p[r][b]);
                }
            if (st > 0) {
                f16x8 hv[4][2];
                pollrows(H1h, st - 1, kp, hv);
                #pragma unroll
                for (int b = 0; b < 4; ++b)
                    #pragma unroll
                    for (int r = 0; r < 8; ++r) {
                        p[r][b] = dot8(wB[r][0], hv[b][0], p[r][b]);
                        p[r][b] = dot8(wB[r][1], hv[b][1], p[r][b]);
                    }
            }
        }

        // ---- butterfly reduce-scatter over 32 kp lanes ----
        float a[32];
        #pragma unroll
        for (int t = 0; t < 32; ++t) a[t] = p[t >> 2][t & 3];
        #pragma unroll
        for (int m = 16; m >= 1; m >>= 1) {
            const bool hi = (kp & m) != 0;
            #pragma unroll
            for (int i = 0; i < m; ++i) {
                float give = hi ? a[i] : a[i + m];
                float got  = __shfl_xor(give, m, 64);
                a[i] = (hi ? a[i + m] : a[i]) + got;
            }
        }
        g_lds[rb_own * 4 + b_own] = a[0] + bsum;
        __syncthreads();

        // ---- activations + h/c update + packed publish (wave 0 only) ----
        if (tid < 64) {
            int jj = tid >> 2, b4 = tid & 3;
            float gi = g_lds[(0  + jj) * 4 + b4];
            float gf = g_lds[(16 + jj) * 4 + b4];
            float gg = g_lds[(32 + jj) * 4 + b4];
            float go = g_lds[(48 + jj) * 4 + b4];
            c_reg = fsigm(gf) * c_reg + fsigm(gi) * ftanh(gg);
            float h2 = fsigm(go) * ftanh(c_reg);
            _Float16 h16 = (_Float16)h2;
            unsigned short hb;
            __builtin_memcpy(&hb, &h16, 2);
            int hv0 = (int)hb;
            int hv1 = __shfl_down(hv0, 4, 64);
            int hv2 = __shfl_down(hv0, 8, 64);
            int hv3 = __shfl_down(hv0, 12, 64);
            if ((jj & 3) == 0) {
                uint64_t pk = (uint64_t)(hv0 & 0xFFFF)
                            | ((uint64_t)(hv1 & 0xFFFF) << 16)
                            | ((uint64_t)(hv2 & 0xFFFF) << 32)
                            | ((uint64_t)(hv3 & 0xFFFF) << 48);
                _Float16* dst = (layer ? H1h : H0h) + (size_t)((st << 2) + b4) * 512 + unit0 + jj;
                __hip_atomic_store((uint64_t*)dst, pk,
                                   __ATOMIC_RELAXED, __HIP_MEMORY_SCOPE_AGENT);
            }
            if (layer) {
                int hu = unit0 + jj;
                __hip_atomic_store(H1 + ((size_t)(b4 * 64 + st)) * 512 + hu, h2,
                                   __ATOMIC_RELAXED, __HIP_MEMORY_SCOPE_AGENT);
            }
        }
        __syncthreads();   // g_lds reuse guard
    }
}

// ---------------------------------------------------------------------------
// joint v2: out[m][n] = b_out[n] + sum_k tanh(henc+hdec)[m][k] * Wo[n][k]
// One block owns 128 m-rows x ALL N=1024 -> tanh computed ONCE (was 8x).
// Phase A: z-tile (128x512 f16) into XOR-swizzled LDS (conflict-free b128).
// Then 8 waves (2m x 4n), nc-loop over 4 chunks of 256 n, K-loop with
// A-frags from LDS and Wo frags streamed from L2 (no Bs LDS, no barriers).
// Grid 512, XCD-chunked bijective block swizzle.
// ---------------------------------------------------------------------------
__global__ void __launch_bounds__(512, 1) k_joint(
        const float* __restrict__ henc, const float* __restrict__ hdec,
        const _Float16* __restrict__ Wo, const float* __restrict__ b_out,
        float* __restrict__ out) {
    __shared__ _Float16 As[128 * 512];   // 128 KB

    const int d   = blockIdx.x;                // 0..511
    const int bm  = (d & 7) * 64 + (d >> 3);   // bijective: 512 = 8*64
    const int m0  = bm * 128;
    const int b   = m0 >> 14;
    const int t0  = (m0 & 16383) >> 6;
    const int tid = threadIdx.x;

    // ---- phase A: As[r][k] = tanh(henc[b][t0+(r>>6)][k] + hdec[b][r&63][k])
    {
        const int r  = tid >> 2;             // 0..127
        const int kq = tid & 3;              // quarter of K
        const int t  = t0 + (r >> 6);
        const int u  = r & 63;
        const float* he = henc + ((size_t)(b * 256 + t)) * 512 + kq * 128;
        const float* hd = hdec + ((size_t)(b * 64 + u)) * 512 + kq * 128;
        _Float16* dst = As + r * 512;
        const int swz = r & 7;
        #pragma unroll
        for (int i = 0; i < 16; ++i) {
            float4 a  = *(const float4*)(he + i * 8);
            float4 a2 = *(const float4*)(he + i * 8 + 4);
            float4 c  = *(const float4*)(hd + i * 8);
            float4 c2 = *(const float4*)(hd + i * 8 + 4);
            f16x8 z8;
            z8[0] = (_Float16)ftanh(a.x + c.x);
            z8[1] = (_Float16)ftanh(a.y + c.y);
            z8[2] = (_Float16)ftanh(a.z + c.z);
            z8[3] = (_Float16)ftanh(a.w + c.w);
            z8[4] = (_Float16)ftanh(a2.x + c2.x);
            z8[5] = (_Float16)ftanh(a2.y + c2.y);
            z8[6] = (_Float16)ftanh(a2.z + c2.z);
            z8[7] = (_Float16)ftanh(a2.w + c2.w);
            int cs = (kq * 16 + i) ^ swz;    // 16B-chunk XOR swizzle
            *(f16x8*)(dst + cs * 8) = z8;
        }
    }
    __syncthreads();

    const int wave = tid >> 6, lane = tid & 63;
    const int l16 = lane & 15, quad = lane >> 4;
    const int wm = wave >> 2;        // 0..1  (64 m-rows)
    const int wn = wave & 3;         // 0..3  (64 n-cols per nc)
    const int swr = l16 & 7;

    for (int nc = 0; nc < 4; ++nc) {
        f32x4 acc[4][4];
        #pragma unroll
        for (int i = 0; i < 4; ++i)
            #pragma unroll
            for (int jx = 0; jx < 4; ++jx) acc[i][jx] = f32x4{0.f, 0.f, 0.f, 0.f};
        const int n_base = nc * 256 + wn * 64;

        #pragma unroll 4
        for (int step = 0; step < 16; ++step) {
            const int k0 = step * 32;
            const int cs = (step * 4 + quad) ^ swr;
            f16x8 af[4], bfv[4];
            #pragma unroll
            for (int i = 0; i < 4; ++i) {
                int row = wm * 64 + i * 16 + l16;
                af[i] = *(const f16x8*)(As + row * 512 + cs * 8);
            }
            #pragma unroll
            for (int jx = 0; jx < 4; ++jx) {
                int n = n_base + jx * 16 + l16;
                bfv[jx] = *(const f16x8*)(Wo + (size_t)n * 512 + k0 + quad * 8);
            }
            #pragma unroll
            for (int i = 0; i < 4; ++i)
                #pragma unroll
                for (int jx = 0; jx < 4; ++jx)
                    acc[i][jx] = __builtin_amdgcn_mfma_f32_16x16x32_f16(af[i], bfv[jx], acc[i][jx], 0, 0, 0);
        }

        #pragma unroll
        for (int i = 0; i < 4; ++i) {
            int mrow = m0 + wm * 64 + i * 16 + quad * 4;
            #pragma unroll
            for (int jx = 0; jx < 4; ++jx) {
                int col = n_base + jx * 16 + l16;
                float bo = b_out[col];
                float* po = out + (size_t)mrow * 1024 + col;
                po[0]    = acc[i][jx][0] + bo;
                po[1024] = acc[i][jx][1] + bo;
                po[2048] = acc[i][jx][2] + bo;
                po[3072] = acc[i][jx][3] + bo;
            }
        }
    }
}

// ---------------------------------------------------------------------------
extern "C" void kernel_launch(void* const* d_in, const int* in_sizes, int n_in,
                              void* d_out, int out_size, void* d_ws, size_t ws_size,
                              hipStream_t stream) {
    const float* hs    = (const float*)d_in[0];
    const int*   ys    = (const int*)d_in[2];
    const float* embed = (const float*)d_in[3];
    const float* wih0  = (const float*)d_in[4];
    const float* whh0  = (const float*)d_in[5];
    const float* bih0  = (const float*)d_in[6];
    const float* bhh0  = (const float*)d_in[7];
    const float* wih1  = (const float*)d_in[8];
    const float* whh1  = (const float*)d_in[9];
    const float* bih1  = (const float*)d_in[10];
    const float* bhh1  = (const float*)d_in[11];
    const float* wenc  = (const float*)d_in[12];
    const float* benc  = (const float*)d_in[13];
    const float* wdec  = (const float*)d_in[14];
    const float* wout  = (const float*)d_in[15];
    const float* bout  = (const float*)d_in[16];
    float* out = (float*)d_out;

    char* ws = (char*)d_ws;
    _Float16* WF     = (_Float16*)(ws);                               // 9 MB
    _Float16* Ebuf16 = (_Float16*)(ws + 9u  * 1024 * 1024);           // 256 KB
    _Float16* H0h    = (_Float16*)(ws + 9u  * 1024 * 1024 + 512u * 1024); // 256 KB f16
    _Float16* H1h    = (_Float16*)(ws + 9u  * 1024 * 1024 + 768u * 1024); // 256 KB f16
    float* H1    = (float*)(ws + 10u * 1024 * 1024);                  // 512 KB
    float* henc  = (float*)(ws + 10u * 1024 * 1024 + 512u * 1024);    // 2 MB
    float* hdec  = (float*)(ws + 12u * 1024 * 1024 + 512u * 1024);    // 512 KB

    // poison h history with f16-NaN sentinel (0xFFFF); finite h never matches
    hipMemsetAsync(ws + 9u * 1024 * 1024 + 512u * 1024, 0xFF, 512u * 1024, stream);
    k_prep_f16<<<2048, 256, 0, stream>>>(wih0, whh0, wih1, whh1, wout, WF, 4718592);
    k_embed<<<256, 256, 0, stream>>>(embed, ys, Ebuf16);
    // blocks 0..63: LSTM; blocks 64..191: henc GEMM on otherwise-idle CUs
    k_lstm<<<192, 256, 0, stream>>>(WF, bih0, bhh0, bih1, bhh1, Ebuf16,
                                    H0h, H1h, H1, hs, wenc, benc, henc);
    k_gemm_small<<<32, 256, 0, stream>>>(H1, wdec, nullptr, hdec);    // M=256
    k_joint<<<512, 512, 0, stream>>>(henc, hdec, WF + (4u << 20), bout, out);
}